// Round 1
// baseline (934.450 us; speedup 1.0000x reference)
//
#include <hip/hip_runtime.h>
#include <hip/hip_cooperative_groups.h>

namespace cg = cooperative_groups;

// Problem constants
#define BATCH   32768
#define DIM     64
#define HID     128
#define NBLOCKS 256        // 1 block per CU (LDS-limited anyway); cooperative co-residency
#define NTHREADS 512       // 8 waves/block
#define NWAVES  8
#define ROWS_PER_BLOCK (BATCH / NBLOCKS)          // 128
#define ROWS_PER_WAVE  (ROWS_PER_BLOCK / NWAVES)  // 16
#define NGROUPS (ROWS_PER_WAVE / 4)               // 4 groups of 4 rows

// LDS layout (floats)
#define LDS_WP1   0
#define LDS_WP2   8192
#define LDS_W3S   24576
#define LDS_SCR   32768                 // 8 waves * 768 floats (ys[64*4] + hb[128*4])
#define LDS_RED   (32768 + 8*768)       // 16 floats
#define LDS_RED2  (LDS_RED + 16)        // 256 floats
#define LDS_FLOATS (LDS_RED2 + 256)     // 39184 floats
#define LDS_BYTES (LDS_FLOATS * 4)      // 156736 B  (<= 160 KiB/CU on gfx950)

typedef float f4 __attribute__((ext_vector_type(4)));
typedef float f2 __attribute__((ext_vector_type(2)));

// dopri5 tableau, rounded to f32 exactly like numpy float32 of the python doubles
__device__ __constant__ // (not actually needed as memory; compiler folds)
const int _dummy = 0;

#define A21 ((float)(1.0/5.0))
#define A31 ((float)(3.0/40.0))
#define A32 ((float)(9.0/40.0))
#define A41 ((float)(44.0/45.0))
#define A42 ((float)(-56.0/15.0))
#define A43 ((float)(32.0/9.0))
#define A51 ((float)(19372.0/6561.0))
#define A52 ((float)(-25360.0/2187.0))
#define A53 ((float)(64448.0/6561.0))
#define A54 ((float)(-212.0/729.0))
#define A61 ((float)(9017.0/3168.0))
#define A62 ((float)(-355.0/33.0))
#define A63 ((float)(46732.0/5247.0))
#define A64 ((float)(49.0/176.0))
#define A65 ((float)(-5103.0/18656.0))
#define BB1 ((float)(35.0/384.0))
#define BB3 ((float)(500.0/1113.0))
#define BB4 ((float)(125.0/192.0))
#define BB5 ((float)(-2187.0/6784.0))
#define BB6 ((float)(11.0/84.0))
// E = B5 - B4, computed as f32(B5_i) - f32(B4_i) to match numpy f32 arithmetic
#define E1 (BB1 - (float)(5179.0/57600.0))
#define E3 (BB3 - (float)(7571.0/16695.0))
#define E4 (BB4 - (float)(393.0/640.0))
#define E5 (BB5 - (float)(-92097.0/339200.0))
#define E6 (BB6 - (float)(187.0/2100.0))
#define E7 (0.0f - (float)(1.0/40.0))

#define RTOL_C 1e-3f
#define ATOL_C 1e-3f
#define SAFETY_C 0.9f
#define MINFAC_C 0.2f
#define MAXFAC_C 10.0f
#define H0_C 0.05f
#define T_DONE ((float)(1.0 - 1e-7))

__device__ __forceinline__ float relu_f(float v) { return fmaxf(v, 0.0f); }

// f(y) for 4 rows at once. Lane owns hidden cols {lane, lane+64} and output col lane.
// ysb: per-wave [64][4] stage-input buffer; hb: per-wave [128][4] activation buffer.
// NOTE: ysb/hb deliberately NOT __restrict__ (reused across inlined calls; must keep
// program order of LDS ops — HW LDS is in-order per wave).
__device__ __forceinline__ void feval4(
    const float* __restrict__ Wp1, const float* __restrict__ Wp2,
    const float* __restrict__ W3s,
    float* ysb, float* hb, const int lane,
    const float b1a, const float b1b, const float b2a, const float b2b, const float b3l,
    const float ys[4], float out[4])
{
    { f4 v; v.x = ys[0]; v.y = ys[1]; v.z = ys[2]; v.w = ys[3];
      *(f4*)(ysb + lane * 4) = v; }
    __builtin_amdgcn_wave_barrier();

    float h1a[4], h1b[4];
#pragma unroll
    for (int r = 0; r < 4; ++r) { h1a[r] = b1a; h1b[r] = b1b; }
#pragma unroll 4
    for (int d = 0; d < 64; ++d) {
        f4 yv = *(const f4*)(ysb + d * 4);                 // broadcast read (4 rows' y_d)
        f2 wv = *(const f2*)(Wp1 + d * 128 + 2 * lane);    // W1[d][lane], W1[d][lane+64]
        h1a[0] += yv.x * wv.x;  h1b[0] += yv.x * wv.y;
        h1a[1] += yv.y * wv.x;  h1b[1] += yv.y * wv.y;
        h1a[2] += yv.z * wv.x;  h1b[2] += yv.z * wv.y;
        h1a[3] += yv.w * wv.x;  h1b[3] += yv.w * wv.y;
    }
    __builtin_amdgcn_wave_barrier();
    { f4 va, vb;
      va.x = relu_f(h1a[0]); va.y = relu_f(h1a[1]); va.z = relu_f(h1a[2]); va.w = relu_f(h1a[3]);
      vb.x = relu_f(h1b[0]); vb.y = relu_f(h1b[1]); vb.z = relu_f(h1b[2]); vb.w = relu_f(h1b[3]);
      *(f4*)(hb + lane * 4) = va;
      *(f4*)(hb + (lane + 64) * 4) = vb; }
    __builtin_amdgcn_wave_barrier();

    float h2a[4], h2b[4];
#pragma unroll
    for (int r = 0; r < 4; ++r) { h2a[r] = b2a; h2b[r] = b2b; }
#pragma unroll 4
    for (int j = 0; j < 128; ++j) {
        f4 hv = *(const f4*)(hb + j * 4);
        f2 wv = *(const f2*)(Wp2 + j * 128 + 2 * lane);    // W2[j][lane], W2[j][lane+64]
        h2a[0] += hv.x * wv.x;  h2b[0] += hv.x * wv.y;
        h2a[1] += hv.y * wv.x;  h2b[1] += hv.y * wv.y;
        h2a[2] += hv.z * wv.x;  h2b[2] += hv.z * wv.y;
        h2a[3] += hv.w * wv.x;  h2b[3] += hv.w * wv.y;
    }
    __builtin_amdgcn_wave_barrier();
    { f4 va, vb;  // all h1 reads are done (in-order per-wave LDS) -> safe to overwrite hb
      va.x = relu_f(h2a[0]); va.y = relu_f(h2a[1]); va.z = relu_f(h2a[2]); va.w = relu_f(h2a[3]);
      vb.x = relu_f(h2b[0]); vb.y = relu_f(h2b[1]); vb.z = relu_f(h2b[2]); vb.w = relu_f(h2b[3]);
      *(f4*)(hb + lane * 4) = va;
      *(f4*)(hb + (lane + 64) * 4) = vb; }
    __builtin_amdgcn_wave_barrier();

    float o[4];
#pragma unroll
    for (int r = 0; r < 4; ++r) o[r] = b3l;
#pragma unroll 4
    for (int j = 0; j < 128; ++j) {
        f4 hv = *(const f4*)(hb + j * 4);
        float w = W3s[j * 64 + lane];                      // W3[j][lane]
        o[0] += hv.x * w; o[1] += hv.y * w; o[2] += hv.z * w; o[3] += hv.w * w;
    }
    __builtin_amdgcn_wave_barrier();
    out[0] = o[0]; out[1] = o[1]; out[2] = o[2]; out[3] = o[3];
}

__global__ __launch_bounds__(NTHREADS, 2) void ode_kernel(
    const float* __restrict__ x,
    const float* __restrict__ gW1, const float* __restrict__ gb1,
    const float* __restrict__ gW2, const float* __restrict__ gb2,
    const float* __restrict__ gW3, const float* __restrict__ gb3,
    float* Y,          // == d_out; holds current y
    float* ws)         // K1 | Y5 | K7 | partials
{
    extern __shared__ float lds[];
    float* Wp1 = lds + LDS_WP1;     // [64][128]  pairs: Wp1[d*128+2c+p] = W1[d][c+64p]
    float* Wp2 = lds + LDS_WP2;     // [128][128] pairs
    float* W3s = lds + LDS_W3S;     // [128][64]
    float* scr = lds + LDS_SCR;
    float* red = lds + LDS_RED;
    float* red2 = lds + LDS_RED2;

    const int tid  = threadIdx.x;
    const int lane = tid & 63;
    const int wid  = tid >> 6;
    const int bid  = blockIdx.x;

    // ---- load + relayout weights into LDS (once for the whole integration) ----
    for (int i = tid; i < 64 * 128; i += NTHREADS) {
        int d = i >> 7, q = i & 127;
        Wp1[i] = gW1[d * 128 + (q >> 1) + 64 * (q & 1)];
    }
    for (int i = tid; i < 128 * 128; i += NTHREADS) {
        int j = i >> 7, q = i & 127;
        Wp2[i] = gW2[j * 128 + (q >> 1) + 64 * (q & 1)];
    }
    for (int i = tid; i < 128 * 64; i += NTHREADS) W3s[i] = gW3[i];
    __syncthreads();

    const float b1a = gb1[lane], b1b = gb1[lane + 64];
    const float b2a = gb2[lane], b2b = gb2[lane + 64];
    const float b3l = gb3[lane];

    float* ysb = scr + wid * 768;
    float* hb  = ysb + 256;

    float* K1   = ws;
    float* Y5   = K1 + BATCH * DIM;
    float* K7   = Y5 + BATCH * DIM;
    float* part = K7 + BATCH * DIM;   // 2*256 floats, ping-pong by iter parity

    cg::grid_group grid = cg::this_grid();

    const int row0 = bid * ROWS_PER_BLOCK + wid * ROWS_PER_WAVE;

    // ---- prepass: y = x; k1 = f(y) ----
    for (int g = 0; g < NGROUPS; ++g) {
        const int rb = row0 + g * 4;
        float yr[4], kr[4];
#pragma unroll
        for (int r = 0; r < 4; ++r) yr[r] = x[(rb + r) * 64 + lane];
        feval4(Wp1, Wp2, W3s, ysb, hb, lane, b1a, b1b, b2a, b2b, b3l, yr, kr);
#pragma unroll
        for (int r = 0; r < 4; ++r) {
            Y[(rb + r) * 64 + lane]  = yr[r];
            K1[(rb + r) * 64 + lane] = kr[r];
        }
    }

    float t = 0.0f, h = H0_C;
    bool done = false;

    for (int iter = 0; iter < 64; ++iter) {
        const float hs = fminf(h, 1.0f - t);
        float sq = 0.0f;

        // ---- phase A: stages 2..6, y5, k7, err partials ----
        for (int g = 0; g < NGROUPS; ++g) {
            const int rb = row0 + g * 4;
            float yr[4], k1r[4], k2r[4], k3r[4], k4r[4], k5r[4], k6r[4], k7r[4], y5r[4], ys[4];
#pragma unroll
            for (int r = 0; r < 4; ++r) {
                yr[r]  = Y[(rb + r) * 64 + lane];
                k1r[r] = K1[(rb + r) * 64 + lane];
            }
#pragma unroll
            for (int r = 0; r < 4; ++r) ys[r] = yr[r] + hs * (A21 * k1r[r]);
            feval4(Wp1, Wp2, W3s, ysb, hb, lane, b1a, b1b, b2a, b2b, b3l, ys, k2r);
#pragma unroll
            for (int r = 0; r < 4; ++r) ys[r] = yr[r] + hs * (A31 * k1r[r] + A32 * k2r[r]);
            feval4(Wp1, Wp2, W3s, ysb, hb, lane, b1a, b1b, b2a, b2b, b3l, ys, k3r);
#pragma unroll
            for (int r = 0; r < 4; ++r) ys[r] = yr[r] + hs * (A41 * k1r[r] + A42 * k2r[r] + A43 * k3r[r]);
            feval4(Wp1, Wp2, W3s, ysb, hb, lane, b1a, b1b, b2a, b2b, b3l, ys, k4r);
#pragma unroll
            for (int r = 0; r < 4; ++r) ys[r] = yr[r] + hs * (A51 * k1r[r] + A52 * k2r[r] + A53 * k3r[r] + A54 * k4r[r]);
            feval4(Wp1, Wp2, W3s, ysb, hb, lane, b1a, b1b, b2a, b2b, b3l, ys, k5r);
#pragma unroll
            for (int r = 0; r < 4; ++r) ys[r] = yr[r] + hs * (A61 * k1r[r] + A62 * k2r[r] + A63 * k3r[r] + A64 * k4r[r] + A65 * k5r[r]);
            feval4(Wp1, Wp2, W3s, ysb, hb, lane, b1a, b1b, b2a, b2b, b3l, ys, k6r);
#pragma unroll
            for (int r = 0; r < 4; ++r) y5r[r] = yr[r] + hs * (BB1 * k1r[r] + BB3 * k3r[r] + BB4 * k4r[r] + BB5 * k5r[r] + BB6 * k6r[r]);
            feval4(Wp1, Wp2, W3s, ysb, hb, lane, b1a, b1b, b2a, b2b, b3l, y5r, k7r);
#pragma unroll
            for (int r = 0; r < 4; ++r) {
                float err = hs * (E1 * k1r[r] + E3 * k3r[r] + E4 * k4r[r] + E5 * k5r[r] + E6 * k6r[r] + E7 * k7r[r]);
                float sc  = ATOL_C + RTOL_C * fmaxf(fabsf(yr[r]), fabsf(y5r[r]));
                float q   = err / sc;
                sq += q * q;
                Y5[(rb + r) * 64 + lane] = y5r[r];
                K7[(rb + r) * 64 + lane] = k7r[r];
            }
        }

        // ---- deterministic global reduction of sq ----
#pragma unroll
        for (int off = 32; off > 0; off >>= 1) sq += __shfl_down(sq, off);
        if (lane == 0) red[wid] = sq;
        __syncthreads();
        if (tid == 0) {
            float s = 0.0f;
            for (int w = 0; w < NWAVES; ++w) s += red[w];
            __hip_atomic_store(&part[(iter & 1) * NBLOCKS + bid], s,
                               __ATOMIC_RELEASE, __HIP_MEMORY_SCOPE_AGENT);
        }
        grid.sync();
        if (tid < NBLOCKS) {
            red2[tid] = __hip_atomic_load(&part[(iter & 1) * NBLOCKS + tid],
                                          __ATOMIC_RELAXED, __HIP_MEMORY_SCOPE_AGENT);
        }
        __syncthreads();
        if (tid == 0) {
            float s = 0.0f;
            for (int b = 0; b < NBLOCKS; ++b) s += red2[b];  // fixed order -> deterministic
            red[8] = s;
        }
        __syncthreads();
        const float tot = red[8];

        const float err_norm = sqrtf(tot * (1.0f / (float)(BATCH * DIM)));
        const bool accept = (err_norm <= 1.0f) && (!done);
        float factor = SAFETY_C * powf(fmaxf(err_norm, 1e-10f), -0.2f);
        factor = fminf(fmaxf(factor, MINFAC_C), MAXFAC_C);

        if (accept) {
            // y = y5 ; k1 = k7 (FSAL)
            for (int g = 0; g < NGROUPS; ++g) {
                const int rb = row0 + g * 4;
#pragma unroll
                for (int r = 0; r < 4; ++r) {
                    Y[(rb + r) * 64 + lane]  = Y5[(rb + r) * 64 + lane];
                    K1[(rb + r) * 64 + lane] = K7[(rb + r) * 64 + lane];
                }
            }
            t = t + hs;
        }
        h = hs * factor;            // old `done` is always false inside the loop
        done = done || (t >= T_DONE);
        if (done) break;            // uniform across grid (identical err_norm everywhere)
    }
    // Y (== d_out) already holds the final state
}

extern "C" void kernel_launch(void* const* d_in, const int* in_sizes, int n_in,
                              void* d_out, int out_size, void* d_ws, size_t ws_size,
                              hipStream_t stream) {
    const float* x  = (const float*)d_in[0];
    const float* W1 = (const float*)d_in[1];
    const float* b1 = (const float*)d_in[2];
    const float* W2 = (const float*)d_in[3];
    const float* b2 = (const float*)d_in[4];
    const float* W3 = (const float*)d_in[5];
    const float* b3 = (const float*)d_in[6];
    float* Y  = (float*)d_out;
    float* ws = (float*)d_ws;

    // ws need: K1 + Y5 + K7 (3 * B*D floats) + 512 partial floats
    const size_t need = (size_t)(3 * BATCH * DIM + 2 * NBLOCKS) * sizeof(float);
    if (ws_size < need) return;  // cannot run safely

    // allow >64KB dynamic LDS (ignore error if unsupported/no-op)
    (void)hipFuncSetAttribute(reinterpret_cast<const void*>(ode_kernel),
                              hipFuncAttributeMaxDynamicSharedMemorySize, LDS_BYTES);

    void* args[] = {(void*)&x, (void*)&W1, (void*)&b1, (void*)&W2, (void*)&b2,
                    (void*)&W3, (void*)&b3, (void*)&Y, (void*)&ws};
    (void)hipLaunchCooperativeKernel(reinterpret_cast<const void*>(ode_kernel),
                                     dim3(NBLOCKS), dim3(NTHREADS),
                                     args, LDS_BYTES, stream);
}

// Round 2
// 841.987 us; speedup vs baseline: 1.1098x; 1.1098x over previous
//
#include <hip/hip_runtime.h>
#include <hip/hip_cooperative_groups.h>

namespace cg = cooperative_groups;

#define BATCH   32768
#define NBLOCKS 256
#define NTHREADS 512
#define NWAVES  8
#define ROWS_PER_BLOCK 128
#define ROWS_PER_WAVE  16

// LDS layout (floats): weights + per-wave scratch = 160 KiB exactly
#define LDS_WP1   0
#define LDS_WP2   8192
#define LDS_W3S   24576
#define LDS_SCR   32768
#define LDS_FLOATS 40960
#define LDS_BYTES (LDS_FLOATS * 4)   // 163840 = 160 KiB

typedef float f2 __attribute__((ext_vector_type(2)));
typedef float f4 __attribute__((ext_vector_type(4)));

#define A21 ((float)(1.0/5.0))
#define A31 ((float)(3.0/40.0))
#define A32 ((float)(9.0/40.0))
#define A41 ((float)(44.0/45.0))
#define A42 ((float)(-56.0/15.0))
#define A43 ((float)(32.0/9.0))
#define A51 ((float)(19372.0/6561.0))
#define A52 ((float)(-25360.0/2187.0))
#define A53 ((float)(64448.0/6561.0))
#define A54 ((float)(-212.0/729.0))
#define A61 ((float)(9017.0/3168.0))
#define A62 ((float)(-355.0/33.0))
#define A63 ((float)(46732.0/5247.0))
#define A64 ((float)(49.0/176.0))
#define A65 ((float)(-5103.0/18656.0))
#define BB1 ((float)(35.0/384.0))
#define BB3 ((float)(500.0/1113.0))
#define BB4 ((float)(125.0/192.0))
#define BB5 ((float)(-2187.0/6784.0))
#define BB6 ((float)(11.0/84.0))
#define E1 (BB1 - (float)(5179.0/57600.0))
#define E3 (BB3 - (float)(7571.0/16695.0))
#define E4 (BB4 - (float)(393.0/640.0))
#define E5 (BB5 - (float)(-92097.0/339200.0))
#define E6 (BB6 - (float)(187.0/2100.0))
#define E7 (0.0f - (float)(1.0/40.0))

#define RTOL_C 1e-3f
#define ATOL_C 1e-3f
#define SAFETY_C 0.9f
#define MINFAC_C 0.2f
#define MAXFAC_C 10.0f
#define H0_C 0.05f
#define T_DONE ((float)(1.0 - 1e-7))

__device__ __forceinline__ float relu_f(float v) { return fmaxf(v, 0.0f); }

// f(y) for 8 rows. Lane owns hidden cols {lane, lane+64} (f2) and output col lane.
// buf: per-wave 1024-float scratch, sequentially reused (ys stage -> h stage -> h stage).
// Safe because a wave's LDS ops to the same buffer execute in program order.
__device__ __forceinline__ void feval8(
    const float* __restrict__ Wp1, const float* __restrict__ Wp2,
    const float* __restrict__ W3s, float* buf, const int lane,
    const f2 b1v, const f2 b2v, const float b3l,
    const f2 ys[4], f2 out[4])
{
    // stage ys: col-major [col][8 rows], col = lane
    {
        f4 q0, q1;
        q0.x = ys[0].x; q0.y = ys[0].y; q0.z = ys[1].x; q0.w = ys[1].y;
        q1.x = ys[2].x; q1.y = ys[2].y; q1.z = ys[3].x; q1.w = ys[3].y;
        *(f4*)(buf + lane * 8)     = q0;
        *(f4*)(buf + lane * 8 + 4) = q1;
    }
    __builtin_amdgcn_wave_barrier();

    f2 h[8];
#pragma unroll
    for (int r = 0; r < 8; ++r) h[r] = b1v;
#pragma unroll 2
    for (int d = 0; d < 64; ++d) {
        f4 ya = *(const f4*)(buf + d * 8);          // rows 0-3 of col d (broadcast)
        f4 yb = *(const f4*)(buf + d * 8 + 4);      // rows 4-7
        f2 wv = *(const f2*)(Wp1 + d * 128 + 2 * lane);
        h[0] += ya.x * wv; h[1] += ya.y * wv; h[2] += ya.z * wv; h[3] += ya.w * wv;
        h[4] += yb.x * wv; h[5] += yb.y * wv; h[6] += yb.z * wv; h[7] += yb.w * wv;
    }
    __builtin_amdgcn_wave_barrier();
    {
        f4 a0, a1, c0, c1;
        a0.x = relu_f(h[0].x); a0.y = relu_f(h[1].x); a0.z = relu_f(h[2].x); a0.w = relu_f(h[3].x);
        a1.x = relu_f(h[4].x); a1.y = relu_f(h[5].x); a1.z = relu_f(h[6].x); a1.w = relu_f(h[7].x);
        c0.x = relu_f(h[0].y); c0.y = relu_f(h[1].y); c0.z = relu_f(h[2].y); c0.w = relu_f(h[3].y);
        c1.x = relu_f(h[4].y); c1.y = relu_f(h[5].y); c1.z = relu_f(h[6].y); c1.w = relu_f(h[7].y);
        *(f4*)(buf + lane * 8)            = a0;
        *(f4*)(buf + lane * 8 + 4)        = a1;
        *(f4*)(buf + (lane + 64) * 8)     = c0;
        *(f4*)(buf + (lane + 64) * 8 + 4) = c1;
    }
    __builtin_amdgcn_wave_barrier();

    f2 g2[8];
#pragma unroll
    for (int r = 0; r < 8; ++r) g2[r] = b2v;
#pragma unroll 2
    for (int j = 0; j < 128; ++j) {
        f4 ha = *(const f4*)(buf + j * 8);
        f4 hc = *(const f4*)(buf + j * 8 + 4);
        f2 wv = *(const f2*)(Wp2 + j * 128 + 2 * lane);
        g2[0] += ha.x * wv; g2[1] += ha.y * wv; g2[2] += ha.z * wv; g2[3] += ha.w * wv;
        g2[4] += hc.x * wv; g2[5] += hc.y * wv; g2[6] += hc.z * wv; g2[7] += hc.w * wv;
    }
    __builtin_amdgcn_wave_barrier();
    {
        f4 a0, a1, c0, c1;
        a0.x = relu_f(g2[0].x); a0.y = relu_f(g2[1].x); a0.z = relu_f(g2[2].x); a0.w = relu_f(g2[3].x);
        a1.x = relu_f(g2[4].x); a1.y = relu_f(g2[5].x); a1.z = relu_f(g2[6].x); a1.w = relu_f(g2[7].x);
        c0.x = relu_f(g2[0].y); c0.y = relu_f(g2[1].y); c0.z = relu_f(g2[2].y); c0.w = relu_f(g2[3].y);
        c1.x = relu_f(g2[4].y); c1.y = relu_f(g2[5].y); c1.z = relu_f(g2[6].y); c1.w = relu_f(g2[7].y);
        *(f4*)(buf + lane * 8)            = a0;
        *(f4*)(buf + lane * 8 + 4)        = a1;
        *(f4*)(buf + (lane + 64) * 8)     = c0;
        *(f4*)(buf + (lane + 64) * 8 + 4) = c1;
    }
    __builtin_amdgcn_wave_barrier();

    f2 o0, o1, o2v, o3;
    o0.x = b3l; o0.y = b3l; o1 = o0; o2v = o0; o3 = o0;
#pragma unroll 2
    for (int j = 0; j < 128; ++j) {
        f4 ha = *(const f4*)(buf + j * 8);
        f4 hc = *(const f4*)(buf + j * 8 + 4);
        float w = W3s[j * 64 + lane];
        f2 p0 = __builtin_shufflevector(ha, ha, 0, 1);
        f2 p1 = __builtin_shufflevector(ha, ha, 2, 3);
        f2 p2 = __builtin_shufflevector(hc, hc, 0, 1);
        f2 p3 = __builtin_shufflevector(hc, hc, 2, 3);
        o0 += p0 * w; o1 += p1 * w; o2v += p2 * w; o3 += p3 * w;
    }
    __builtin_amdgcn_wave_barrier();
    out[0] = o0; out[1] = o1; out[2] = o2v; out[3] = o3;
}

__global__ __launch_bounds__(NTHREADS, 2) void ode_kernel(
    const float* __restrict__ x,
    const float* __restrict__ gW1, const float* __restrict__ gb1,
    const float* __restrict__ gW2, const float* __restrict__ gb2,
    const float* __restrict__ gW3, const float* __restrict__ gb3,
    float* __restrict__ Y, float* __restrict__ ws)
{
    extern __shared__ float lds[];
    float* Wp1 = lds + LDS_WP1;   // [64][128] pair layout: Wp1[d*128+2c+p] = W1[d][c+64p]
    float* Wp2 = lds + LDS_WP2;   // [128][128] pair layout
    float* W3s = lds + LDS_W3S;   // [128][64]

    const int tid  = threadIdx.x;
    const int lane = tid & 63;
    const int wid  = tid >> 6;
    const int bid  = blockIdx.x;

    for (int i = tid; i < 64 * 128; i += NTHREADS) {
        int d = i >> 7, q = i & 127;
        Wp1[i] = gW1[d * 128 + (q >> 1) + 64 * (q & 1)];
    }
    for (int i = tid; i < 128 * 128; i += NTHREADS) {
        int j = i >> 7, q = i & 127;
        Wp2[i] = gW2[j * 128 + (q >> 1) + 64 * (q & 1)];
    }
    for (int i = tid; i < 128 * 64; i += NTHREADS) W3s[i] = gW3[i];
    __syncthreads();

    f2 b1v; b1v.x = gb1[lane]; b1v.y = gb1[lane + 64];
    f2 b2v; b2v.x = gb2[lane]; b2v.y = gb2[lane + 64];
    const float b3l = gb3[lane];

    float* buf = lds + LDS_SCR + wid * 1024;   // private per wave
    float* wavepart = ws;                       // [2][2048] ping-pong

    cg::grid_group grid = cg::this_grid();
    const int row0 = bid * ROWS_PER_BLOCK + wid * ROWS_PER_WAVE;

    // persistent per-lane state: 16 rows as f2 row-pairs, col = lane
    f2 y[2][4], k1[2][4];

    // ---- prepass: y = x; k1 = f(y) ----
#pragma unroll
    for (int g = 0; g < 2; ++g) {
        const int rb = row0 + g * 8;
        f2 ysv[4], outv[4];
#pragma unroll
        for (int r = 0; r < 4; ++r) {
            ysv[r].x = x[(rb + 2 * r) * 64 + lane];
            ysv[r].y = x[(rb + 2 * r + 1) * 64 + lane];
            y[g][r] = ysv[r];
        }
        feval8(Wp1, Wp2, W3s, buf, lane, b1v, b2v, b3l, ysv, outv);
#pragma unroll
        for (int r = 0; r < 4; ++r) k1[g][r] = outv[r];
    }

    float t = 0.0f, h = H0_C;
    bool done = false;

#pragma unroll 1
    for (int iter = 0; iter < 64; ++iter) {
        const float hs = fminf(h, 1.0f - t);
        float sq = 0.0f;
        f2 y5[2][4], k7[2][4];

#pragma unroll
        for (int g = 0; g < 2; ++g) {
            f2 k2[4], k3[4], k4[4], k5[4], k6[4], ysv[4], outv[4];
#pragma unroll 1
            for (int s = 0; s < 6; ++s) {
                switch (s) {
                case 0:
#pragma unroll
                    for (int r = 0; r < 4; ++r) ysv[r] = y[g][r] + hs * (A21 * k1[g][r]);
                    break;
                case 1:
#pragma unroll
                    for (int r = 0; r < 4; ++r) ysv[r] = y[g][r] + hs * (A31 * k1[g][r] + A32 * k2[r]);
                    break;
                case 2:
#pragma unroll
                    for (int r = 0; r < 4; ++r) ysv[r] = y[g][r] + hs * (A41 * k1[g][r] + A42 * k2[r] + A43 * k3[r]);
                    break;
                case 3:
#pragma unroll
                    for (int r = 0; r < 4; ++r) ysv[r] = y[g][r] + hs * (A51 * k1[g][r] + A52 * k2[r] + A53 * k3[r] + A54 * k4[r]);
                    break;
                case 4:
#pragma unroll
                    for (int r = 0; r < 4; ++r) ysv[r] = y[g][r] + hs * (A61 * k1[g][r] + A62 * k2[r] + A63 * k3[r] + A64 * k4[r] + A65 * k5[r]);
                    break;
                default:
#pragma unroll
                    for (int r = 0; r < 4; ++r) {
                        ysv[r] = y[g][r] + hs * (BB1 * k1[g][r] + BB3 * k3[r] + BB4 * k4[r] + BB5 * k5[r] + BB6 * k6[r]);
                        y5[g][r] = ysv[r];
                    }
                    break;
                }
                feval8(Wp1, Wp2, W3s, buf, lane, b1v, b2v, b3l, ysv, outv);
                switch (s) {
                case 0:
#pragma unroll
                    for (int r = 0; r < 4; ++r) k2[r] = outv[r];
                    break;
                case 1:
#pragma unroll
                    for (int r = 0; r < 4; ++r) k3[r] = outv[r];
                    break;
                case 2:
#pragma unroll
                    for (int r = 0; r < 4; ++r) k4[r] = outv[r];
                    break;
                case 3:
#pragma unroll
                    for (int r = 0; r < 4; ++r) k5[r] = outv[r];
                    break;
                case 4:
#pragma unroll
                    for (int r = 0; r < 4; ++r) k6[r] = outv[r];
                    break;
                default:
#pragma unroll
                    for (int r = 0; r < 4; ++r) k7[g][r] = outv[r];
                    break;
                }
            }
            // error partials
#pragma unroll
            for (int r = 0; r < 4; ++r) {
                f2 er = hs * (E1 * k1[g][r] + E3 * k3[r] + E4 * k4[r] + E5 * k5[r] + E6 * k6[r] + E7 * k7[g][r]);
                f2 sc;
                sc.x = ATOL_C + RTOL_C * fmaxf(fabsf(y[g][r].x), fabsf(y5[g][r].x));
                sc.y = ATOL_C + RTOL_C * fmaxf(fabsf(y[g][r].y), fabsf(y5[g][r].y));
                f2 q = er / sc;
                sq += q.x * q.x + q.y * q.y;
            }
        }

        // wave butterfly reduce (bitwise identical on all lanes)
#pragma unroll
        for (int off = 32; off > 0; off >>= 1) sq += __shfl_xor(sq, off);
        if (lane == 0)
            __hip_atomic_store(&wavepart[(iter & 1) * 2048 + bid * 8 + wid], sq,
                               __ATOMIC_RELEASE, __HIP_MEMORY_SCOPE_AGENT);
        grid.sync();

        // every wave redundantly sums all 2048 partials in identical fixed order
        float psum = 0.0f;
        const float* wp = wavepart + (iter & 1) * 2048;
#pragma unroll 4
        for (int k = 0; k < 32; ++k)
            psum += __hip_atomic_load(&wp[lane + 64 * k], __ATOMIC_RELAXED, __HIP_MEMORY_SCOPE_AGENT);
#pragma unroll
        for (int off = 32; off > 0; off >>= 1) psum += __shfl_xor(psum, off);
        const float tot = psum;

        const float err_norm = sqrtf(tot * (1.0f / (float)(BATCH * 64)));
        const bool accept = (err_norm <= 1.0f) && (!done);
        float factor = SAFETY_C * powf(fmaxf(err_norm, 1e-10f), -0.2f);
        factor = fminf(fmaxf(factor, MINFAC_C), MAXFAC_C);

        if (accept) {
#pragma unroll
            for (int g = 0; g < 2; ++g)
#pragma unroll
                for (int r = 0; r < 4; ++r) { y[g][r] = y5[g][r]; k1[g][r] = k7[g][r]; }
            t = t + hs;
        }
        h = hs * factor;
        done = done || (t >= T_DONE);
        if (done) break;   // uniform: identical err_norm in every block
    }

    // final store
#pragma unroll
    for (int g = 0; g < 2; ++g) {
        const int rb = row0 + g * 8;
#pragma unroll
        for (int r = 0; r < 4; ++r) {
            Y[(rb + 2 * r) * 64 + lane]     = y[g][r].x;
            Y[(rb + 2 * r + 1) * 64 + lane] = y[g][r].y;
        }
    }
}

extern "C" void kernel_launch(void* const* d_in, const int* in_sizes, int n_in,
                              void* d_out, int out_size, void* d_ws, size_t ws_size,
                              hipStream_t stream) {
    const float* x  = (const float*)d_in[0];
    const float* W1 = (const float*)d_in[1];
    const float* b1 = (const float*)d_in[2];
    const float* W2 = (const float*)d_in[3];
    const float* b2 = (const float*)d_in[4];
    const float* W3 = (const float*)d_in[5];
    const float* b3 = (const float*)d_in[6];
    float* Y  = (float*)d_out;
    float* ws = (float*)d_ws;

    const size_t need = (size_t)(2 * 2048) * sizeof(float);
    if (ws_size < need) return;

    (void)hipFuncSetAttribute(reinterpret_cast<const void*>(ode_kernel),
                              hipFuncAttributeMaxDynamicSharedMemorySize, LDS_BYTES);

    void* args[] = {(void*)&x, (void*)&W1, (void*)&b1, (void*)&W2, (void*)&b2,
                    (void*)&W3, (void*)&b3, (void*)&Y, (void*)&ws};
    (void)hipLaunchCooperativeKernel(reinterpret_cast<const void*>(ode_kernel),
                                     dim3(NBLOCKS), dim3(NTHREADS),
                                     args, LDS_BYTES, stream);
}

// Round 3
// 432.621 us; speedup vs baseline: 2.1600x; 1.9462x over previous
//
#include <hip/hip_runtime.h>
#include <hip/hip_cooperative_groups.h>

namespace cg = cooperative_groups;

#define BATCH   32768
#define NBLOCKS 256
#define NTHREADS 512
#define NWAVES  8

// LDS byte layout:
//   [0, 16384)        W1^T frags  (8 Mtiles x 2 Ktiles x 1KB)
//   [16384, 49152)    W2^T frags  (8 x 4 x 1KB)
//   [49152, 65536)    W3^T frags  (4 x 4 x 1KB)
//   [65536, 131072)   8 waves x 8KB scratch
//   [131072, 132352)  bias f32: b1[128] b2[128] b3[64]
#define LDS_BYTES 132352

typedef short    bf16x8 __attribute__((ext_vector_type(8)));
typedef float    f32x4  __attribute__((ext_vector_type(4)));
typedef unsigned u32x2  __attribute__((ext_vector_type(2)));
typedef float    f4v    __attribute__((ext_vector_type(4)));

#define A21 ((float)(1.0/5.0))
#define A31 ((float)(3.0/40.0))
#define A32 ((float)(9.0/40.0))
#define A41 ((float)(44.0/45.0))
#define A42 ((float)(-56.0/15.0))
#define A43 ((float)(32.0/9.0))
#define A51 ((float)(19372.0/6561.0))
#define A52 ((float)(-25360.0/2187.0))
#define A53 ((float)(64448.0/6561.0))
#define A54 ((float)(-212.0/729.0))
#define A61 ((float)(9017.0/3168.0))
#define A62 ((float)(-355.0/33.0))
#define A63 ((float)(46732.0/5247.0))
#define A64 ((float)(49.0/176.0))
#define A65 ((float)(-5103.0/18656.0))
#define BB1 ((float)(35.0/384.0))
#define BB3 ((float)(500.0/1113.0))
#define BB4 ((float)(125.0/192.0))
#define BB5 ((float)(-2187.0/6784.0))
#define BB6 ((float)(11.0/84.0))
#define E1 (BB1 - (float)(5179.0/57600.0))
#define E3 (BB3 - (float)(7571.0/16695.0))
#define E4 (BB4 - (float)(393.0/640.0))
#define E5 (BB5 - (float)(-92097.0/339200.0))
#define E6 (BB6 - (float)(187.0/2100.0))
#define E7 (0.0f - (float)(1.0/40.0))

#define RTOL_C 1e-3f
#define ATOL_C 1e-3f
#define SAFETY_C 0.9f
#define MINFAC_C 0.2f
#define MAXFAC_C 10.0f
#define H0_C 0.05f
#define T_DONE ((float)(1.0 - 1e-7))

// bf16 round-to-nearest-even helpers (bit pattern in low 16)
__device__ __forceinline__ unsigned bfr(float x) {
    unsigned u = __builtin_bit_cast(unsigned, x);
    return (u + 0x7fffu + ((u >> 16) & 1u)) >> 16;
}
__device__ __forceinline__ unsigned pack2bf(float a, float b) {
    return bfr(a) | (bfr(b) << 16);
}
__device__ __forceinline__ float bfhi(float a) {
    return __builtin_bit_cast(float, bfr(a) << 16);
}

// f(y) for the wave's 16 batch rows, fully MFMA.
// State layout: lane (b = lane&15, g = lane>>4) owns batch row b, dims m*16+4g+r.
// Computes C^T = W^T . Y^T per layer; weights pre-staged as frag-linear bf16 tiles.
// scr: per-wave 8KB; lifetimes: ybuf[0,4K) -> h1_lo[0,4K)+h1_hi[4K,8K) -> h2[0,4K).
// Same-wave LDS ops complete in program order (HW FIFO); wave_barrier stops
// compiler reordering across the cross-lane write->read boundaries.
__device__ __forceinline__ void feval16(
    const char* __restrict__ wf, const float* __restrict__ biasf,
    char* scr, const int lane, const int b, const int g, const int swzx,
    const float (&ys)[16], float (&kout)[16])
{
    // ---- stage ys -> ybuf (hi/lo planes, [16][64] bf16, swizzled) ----
#pragma unroll
    for (int m = 0; m < 4; ++m) {
        const float a0 = ys[4*m], a1 = ys[4*m+1], a2 = ys[4*m+2], a3 = ys[4*m+3];
        u32x2 vh, vl;
        vh.x = pack2bf(a0, a1); vh.y = pack2bf(a2, a3);
        vl.x = pack2bf(a0 - bfhi(a0), a1 - bfhi(a1));
        vl.y = pack2bf(a2 - bfhi(a2), a3 - bfhi(a3));
        const int off = (b*128 + (m*16 + 4*g)*2) ^ swzx;
        *(u32x2*)(scr + off)        = vh;
        *(u32x2*)(scr + 2048 + off) = vl;
    }
    __builtin_amdgcn_wave_barrier();
    // ---- L1: B-frags from ybuf ----
    bf16x8 Bh0, Bh1, Bl0, Bl1;
    {
        const int o0 = (b*128 + 16*g) ^ swzx;
        const int o1 = (b*128 + 64 + 16*g) ^ swzx;
        Bh0 = *(const bf16x8*)(scr + o0);
        Bh1 = *(const bf16x8*)(scr + o1);
        Bl0 = *(const bf16x8*)(scr + 2048 + o0);
        Bl1 = *(const bf16x8*)(scr + 2048 + o1);
    }
    __builtin_amdgcn_wave_barrier();
#pragma unroll
    for (int m = 0; m < 8; ++m) {
        f32x4 acc = {0.f, 0.f, 0.f, 0.f};
        const bf16x8 A0 = *(const bf16x8*)(wf + (m*2+0)*1024 + lane*16);
        const bf16x8 A1 = *(const bf16x8*)(wf + (m*2+1)*1024 + lane*16);
        acc = __builtin_amdgcn_mfma_f32_16x16x32_bf16(A0, Bh0, acc, 0, 0, 0);
        acc = __builtin_amdgcn_mfma_f32_16x16x32_bf16(A1, Bh1, acc, 0, 0, 0);
        acc = __builtin_amdgcn_mfma_f32_16x16x32_bf16(A0, Bl0, acc, 0, 0, 0);
        acc = __builtin_amdgcn_mfma_f32_16x16x32_bf16(A1, Bl1, acc, 0, 0, 0);
        const f4v bia = *(const f4v*)(biasf + m*16 + 4*g);
        const float v0 = fmaxf(acc[0] + bia.x, 0.f);
        const float v1 = fmaxf(acc[1] + bia.y, 0.f);
        const float v2 = fmaxf(acc[2] + bia.z, 0.f);
        const float v3 = fmaxf(acc[3] + bia.w, 0.f);
        u32x2 vh, vl;
        vh.x = pack2bf(v0, v1); vh.y = pack2bf(v2, v3);
        vl.x = pack2bf(v0 - bfhi(v0), v1 - bfhi(v1));
        vl.y = pack2bf(v2 - bfhi(v2), v3 - bfhi(v3));
        const int off = (b*256 + (m*16 + 4*g)*2) ^ swzx;
        *(u32x2*)(scr + 4096 + off) = vh;     // h1_hi
        *(u32x2*)(scr + off)        = vl;     // h1_lo (ybuf dead)
    }
    __builtin_amdgcn_wave_barrier();
    // ---- L2 ----
    bf16x8 B2h[4], B2l[4];
#pragma unroll
    for (int kt = 0; kt < 4; ++kt) {
        const int off = (b*256 + 64*kt + 16*g) ^ swzx;
        B2h[kt] = *(const bf16x8*)(scr + 4096 + off);
        B2l[kt] = *(const bf16x8*)(scr + off);
    }
    __builtin_amdgcn_wave_barrier();
#pragma unroll
    for (int m = 0; m < 8; ++m) {
        f32x4 acc = {0.f, 0.f, 0.f, 0.f};
#pragma unroll
        for (int kt = 0; kt < 4; ++kt) {
            const bf16x8 A = *(const bf16x8*)(wf + 16384 + (m*4+kt)*1024 + lane*16);
            acc = __builtin_amdgcn_mfma_f32_16x16x32_bf16(A, B2h[kt], acc, 0, 0, 0);
            acc = __builtin_amdgcn_mfma_f32_16x16x32_bf16(A, B2l[kt], acc, 0, 0, 0);
        }
        const f4v bia = *(const f4v*)(biasf + 128 + m*16 + 4*g);
        const float v0 = fmaxf(acc[0] + bia.x, 0.f);
        const float v1 = fmaxf(acc[1] + bia.y, 0.f);
        const float v2 = fmaxf(acc[2] + bia.z, 0.f);
        const float v3 = fmaxf(acc[3] + bia.w, 0.f);
        u32x2 vh;
        vh.x = pack2bf(v0, v1); vh.y = pack2bf(v2, v3);
        const int off = (b*256 + (m*16 + 4*g)*2) ^ swzx;
        *(u32x2*)(scr + off) = vh;            // h2_hi (h1_lo dead)
    }
    __builtin_amdgcn_wave_barrier();
    // ---- L3 ----
    bf16x8 B3[4];
#pragma unroll
    for (int kt = 0; kt < 4; ++kt)
        B3[kt] = *(const bf16x8*)(scr + ((b*256 + 64*kt + 16*g) ^ swzx));
    __builtin_amdgcn_wave_barrier();
#pragma unroll
    for (int m = 0; m < 4; ++m) {
        f32x4 acc = {0.f, 0.f, 0.f, 0.f};
#pragma unroll
        for (int kt = 0; kt < 4; ++kt) {
            const bf16x8 A = *(const bf16x8*)(wf + 49152 + (m*4+kt)*1024 + lane*16);
            acc = __builtin_amdgcn_mfma_f32_16x16x32_bf16(A, B3[kt], acc, 0, 0, 0);
        }
        const f4v bia = *(const f4v*)(biasf + 256 + m*16 + 4*g);
        kout[4*m+0] = acc[0] + bia.x;
        kout[4*m+1] = acc[1] + bia.y;
        kout[4*m+2] = acc[2] + bia.z;
        kout[4*m+3] = acc[3] + bia.w;
    }
}

__global__ __launch_bounds__(NTHREADS, 2) void ode_kernel(
    const float* __restrict__ x,
    const float* __restrict__ gW1, const float* __restrict__ gb1,
    const float* __restrict__ gW2, const float* __restrict__ gb2,
    const float* __restrict__ gW3, const float* __restrict__ gb3,
    float* __restrict__ Y, float* __restrict__ ws)
{
    extern __shared__ float lds[];
    char*  ldsb  = (char*)lds;
    short* wfrag = (short*)ldsb;
    float* biasf = (float*)(ldsb + 131072);

    const int tid  = threadIdx.x;
    const int lane = tid & 63;
    const int wid  = tid >> 6;
    const int bid  = blockIdx.x;
    const int b    = lane & 15;
    const int g    = lane >> 4;
    const int swzx = (b & 7) << 4;

    // ---- stage weights as frag-linear bf16 tiles (once) ----
    // A-frag of W^T tile (m,kt): elem[lane*8+j] = W[kt*32+(lane>>4)*8+j][m*16+(lane&15)]
    for (int i = tid; i < 8192; i += NTHREADS) {       // W1: 16 tiles (m*2+kt)
        const int t = i >> 9, l = (i >> 3) & 63, j = i & 7;
        const int m = t >> 1, kt = t & 1;
        const int row = kt*32 + (l>>4)*8 + j, col = m*16 + (l&15);
        wfrag[i] = (short)bfr(gW1[row*128 + col]);
    }
    for (int i = tid; i < 16384; i += NTHREADS) {      // W2: 32 tiles (m*4+kt)
        const int t = i >> 9, l = (i >> 3) & 63, j = i & 7;
        const int m = t >> 2, kt = t & 3;
        const int row = kt*32 + (l>>4)*8 + j, col = m*16 + (l&15);
        wfrag[8192 + i] = (short)bfr(gW2[row*128 + col]);
    }
    for (int i = tid; i < 8192; i += NTHREADS) {       // W3: 16 tiles (m*4+kt)
        const int t = i >> 9, l = (i >> 3) & 63, j = i & 7;
        const int m = t >> 2, kt = t & 3;
        const int row = kt*32 + (l>>4)*8 + j, col = m*16 + (l&15);
        wfrag[24576 + i] = (short)bfr(gW3[row*64 + col]);
    }
    for (int i = tid; i < 128; i += NTHREADS) biasf[i]       = gb1[i];
    for (int i = tid; i < 128; i += NTHREADS) biasf[128 + i] = gb2[i];
    for (int i = tid; i < 64;  i += NTHREADS) biasf[256 + i] = gb3[i];
    __syncthreads();

    char* scr = ldsb + 65536 + wid * 8192;
    float* wavepart = ws;                     // [2][2048] ping-pong

    cg::grid_group grid = cg::this_grid();
    const int row0 = bid * 128 + wid * 16;

    // persistent state: lane owns batch row0+b, dims m*16+4g+r  (idx = m*4+r)
    float y[16], k1[16];

    // ---- prepass: y = x; k1 = f(y) ----
    {
        float ysv[16];
#pragma unroll
        for (int m = 0; m < 4; ++m) {
            const f4v v = *(const f4v*)(x + (row0 + b) * 64 + m*16 + 4*g);
            ysv[4*m+0] = v.x; ysv[4*m+1] = v.y; ysv[4*m+2] = v.z; ysv[4*m+3] = v.w;
        }
#pragma unroll
        for (int i = 0; i < 16; ++i) y[i] = ysv[i];
        feval16(ldsb, biasf, scr, lane, b, g, swzx, ysv, k1);
    }

    float t = 0.0f, h = H0_C;
    bool done = false;

#pragma unroll 1
    for (int iter = 0; iter < 64; ++iter) {
        const float hs = fminf(h, 1.0f - t);
        float sq = 0.0f;
        float k2[16], k3[16], k4[16], k5[16], k6[16], k7[16], y5[16];

        {
            float ysv[16], outv[16];
#pragma unroll 1
            for (int s = 0; s < 6; ++s) {
                switch (s) {
                case 0:
#pragma unroll
                    for (int i = 0; i < 16; ++i) ysv[i] = y[i] + hs * (A21 * k1[i]);
                    break;
                case 1:
#pragma unroll
                    for (int i = 0; i < 16; ++i) ysv[i] = y[i] + hs * (A31 * k1[i] + A32 * k2[i]);
                    break;
                case 2:
#pragma unroll
                    for (int i = 0; i < 16; ++i) ysv[i] = y[i] + hs * (A41 * k1[i] + A42 * k2[i] + A43 * k3[i]);
                    break;
                case 3:
#pragma unroll
                    for (int i = 0; i < 16; ++i) ysv[i] = y[i] + hs * (A51 * k1[i] + A52 * k2[i] + A53 * k3[i] + A54 * k4[i]);
                    break;
                case 4:
#pragma unroll
                    for (int i = 0; i < 16; ++i) ysv[i] = y[i] + hs * (A61 * k1[i] + A62 * k2[i] + A63 * k3[i] + A64 * k4[i] + A65 * k5[i]);
                    break;
                default:
#pragma unroll
                    for (int i = 0; i < 16; ++i) {
                        ysv[i] = y[i] + hs * (BB1 * k1[i] + BB3 * k3[i] + BB4 * k4[i] + BB5 * k5[i] + BB6 * k6[i]);
                        y5[i] = ysv[i];
                    }
                    break;
                }
                feval16(ldsb, biasf, scr, lane, b, g, swzx, ysv, outv);
                switch (s) {
                case 0:
#pragma unroll
                    for (int i = 0; i < 16; ++i) k2[i] = outv[i];
                    break;
                case 1:
#pragma unroll
                    for (int i = 0; i < 16; ++i) k3[i] = outv[i];
                    break;
                case 2:
#pragma unroll
                    for (int i = 0; i < 16; ++i) k4[i] = outv[i];
                    break;
                case 3:
#pragma unroll
                    for (int i = 0; i < 16; ++i) k5[i] = outv[i];
                    break;
                case 4:
#pragma unroll
                    for (int i = 0; i < 16; ++i) k6[i] = outv[i];
                    break;
                default:
#pragma unroll
                    for (int i = 0; i < 16; ++i) k7[i] = outv[i];
                    break;
                }
            }
        }

        // error partials
#pragma unroll
        for (int i = 0; i < 16; ++i) {
            const float er = hs * (E1 * k1[i] + E3 * k3[i] + E4 * k4[i] + E5 * k5[i] + E6 * k6[i] + E7 * k7[i]);
            const float sc = ATOL_C + RTOL_C * fmaxf(fabsf(y[i]), fabsf(y5[i]));
            const float q = er / sc;
            sq += q * q;
        }

        // wave butterfly reduce (bitwise identical on all lanes)
#pragma unroll
        for (int off = 32; off > 0; off >>= 1) sq += __shfl_xor(sq, off);
        if (lane == 0)
            __hip_atomic_store(&wavepart[(iter & 1) * 2048 + bid * 8 + wid], sq,
                               __ATOMIC_RELEASE, __HIP_MEMORY_SCOPE_AGENT);
        grid.sync();

        // every wave redundantly sums all 2048 partials in identical fixed order
        float psum = 0.0f;
        const float* wp = wavepart + (iter & 1) * 2048;
#pragma unroll 4
        for (int k = 0; k < 32; ++k)
            psum += __hip_atomic_load(&wp[lane + 64 * k], __ATOMIC_RELAXED, __HIP_MEMORY_SCOPE_AGENT);
#pragma unroll
        for (int off = 32; off > 0; off >>= 1) psum += __shfl_xor(psum, off);
        const float tot = psum;

        const float err_norm = sqrtf(tot * (1.0f / (float)(BATCH * 64)));
        const bool accept = (err_norm <= 1.0f) && (!done);
        float factor = SAFETY_C * powf(fmaxf(err_norm, 1e-10f), -0.2f);
        factor = fminf(fmaxf(factor, MINFAC_C), MAXFAC_C);

        if (accept) {
#pragma unroll
            for (int i = 0; i < 16; ++i) { y[i] = y5[i]; k1[i] = k7[i]; }
            t = t + hs;
        }
        h = hs * factor;
        done = done || (t >= T_DONE);
        if (done) break;   // uniform: identical err_norm in every block
    }

    // final store
#pragma unroll
    for (int m = 0; m < 4; ++m) {
        f4v v;
        v.x = y[4*m+0]; v.y = y[4*m+1]; v.z = y[4*m+2]; v.w = y[4*m+3];
        *(f4v*)(Y + (row0 + b) * 64 + m*16 + 4*g) = v;
    }
}

extern "C" void kernel_launch(void* const* d_in, const int* in_sizes, int n_in,
                              void* d_out, int out_size, void* d_ws, size_t ws_size,
                              hipStream_t stream) {
    const float* x  = (const float*)d_in[0];
    const float* W1 = (const float*)d_in[1];
    const float* b1 = (const float*)d_in[2];
    const float* W2 = (const float*)d_in[3];
    const float* b2 = (const float*)d_in[4];
    const float* W3 = (const float*)d_in[5];
    const float* b3 = (const float*)d_in[6];
    float* Y  = (float*)d_out;
    float* ws = (float*)d_ws;

    const size_t need = (size_t)(2 * 2048) * sizeof(float);
    if (ws_size < need) return;

    (void)hipFuncSetAttribute(reinterpret_cast<const void*>(ode_kernel),
                              hipFuncAttributeMaxDynamicSharedMemorySize, LDS_BYTES);

    void* args[] = {(void*)&x, (void*)&W1, (void*)&b1, (void*)&W2, (void*)&b2,
                    (void*)&W3, (void*)&b3, (void*)&Y, (void*)&ws};
    (void)hipLaunchCooperativeKernel(reinterpret_cast<const void*>(ode_kernel),
                                     dim3(NBLOCKS), dim3(NTHREADS),
                                     args, LDS_BYTES, stream);
}

// Round 4
// 279.724 us; speedup vs baseline: 3.3406x; 1.5466x over previous
//
#include <hip/hip_runtime.h>
#include <hip/hip_cooperative_groups.h>

namespace cg = cooperative_groups;

#define BATCH   32768
#define NBLOCKS 256
#define NTHREADS 512
#define NWAVES  8

// LDS byte layout:
//   [0, 16384)        W1^T frags  (8 Mtiles x 2 Ktiles x 1KB)
//   [16384, 49152)    W2^T frags  (8 x 4 x 1KB)
//   [49152, 65536)    W3^T frags  (4 x 4 x 1KB)
//   [65536, 131072)   8 waves x 8KB scratch
//   [131072, 132352)  bias f32: b1[128] b2[128] b3[64]
#define LDS_BYTES 132352

typedef short    bf16x8 __attribute__((ext_vector_type(8)));
typedef float    f32x4  __attribute__((ext_vector_type(4)));
typedef unsigned u32x2  __attribute__((ext_vector_type(2)));
typedef float    f4v    __attribute__((ext_vector_type(4)));

#define A21 ((float)(1.0/5.0))
#define A31 ((float)(3.0/40.0))
#define A32 ((float)(9.0/40.0))
#define A41 ((float)(44.0/45.0))
#define A42 ((float)(-56.0/15.0))
#define A43 ((float)(32.0/9.0))
#define A51 ((float)(19372.0/6561.0))
#define A52 ((float)(-25360.0/2187.0))
#define A53 ((float)(64448.0/6561.0))
#define A54 ((float)(-212.0/729.0))
#define A61 ((float)(9017.0/3168.0))
#define A62 ((float)(-355.0/33.0))
#define A63 ((float)(46732.0/5247.0))
#define A64 ((float)(49.0/176.0))
#define A65 ((float)(-5103.0/18656.0))
#define BB1 ((float)(35.0/384.0))
#define BB3 ((float)(500.0/1113.0))
#define BB4 ((float)(125.0/192.0))
#define BB5 ((float)(-2187.0/6784.0))
#define BB6 ((float)(11.0/84.0))
#define E1 (BB1 - (float)(5179.0/57600.0))
#define E3 (BB3 - (float)(7571.0/16695.0))
#define E4 (BB4 - (float)(393.0/640.0))
#define E5 (BB5 - (float)(-92097.0/339200.0))
#define E6 (BB6 - (float)(187.0/2100.0))
#define E7 (0.0f - (float)(1.0/40.0))

#define RTOL_C 1e-3f
#define ATOL_C 1e-3f
#define SAFETY_C 0.9f
#define MINFAC_C 0.2f
#define MAXFAC_C 10.0f
#define H0_C 0.05f
#define T_DONE ((float)(1.0 - 1e-7))

// bf16 round-to-nearest-even helpers (bit pattern in low 16)
__device__ __forceinline__ unsigned bfr(float x) {
    unsigned u = __builtin_bit_cast(unsigned, x);
    return (u + 0x7fffu + ((u >> 16) & 1u)) >> 16;
}
__device__ __forceinline__ unsigned pack2bf(float a, float b) {
    return bfr(a) | (bfr(b) << 16);
}
__device__ __forceinline__ float bfhi(float a) {
    return __builtin_bit_cast(float, bfr(a) << 16);
}

// f(y) for the wave's 16 batch rows, fully MFMA.
// State layout: lane (b = lane&15, g = lane>>4) owns batch row b, dims m*16+4g+r.
// Computes C^T = W^T . Y^T per layer; weights pre-staged as frag-linear bf16 tiles.
// scr: per-wave 8KB; lifetimes: ybuf[0,4K) -> h1_lo[0,4K)+h1_hi[4K,8K) -> h2[0,4K).
__device__ __forceinline__ void feval16(
    const char* __restrict__ wf, const float* __restrict__ biasf,
    char* scr, const int lane, const int b, const int g, const int swzx,
    const float (&ys)[16], float (&kout)[16])
{
    // ---- stage ys -> ybuf (hi/lo planes, [16][64] bf16, swizzled) ----
#pragma unroll
    for (int m = 0; m < 4; ++m) {
        const float a0 = ys[4*m], a1 = ys[4*m+1], a2 = ys[4*m+2], a3 = ys[4*m+3];
        u32x2 vh, vl;
        vh.x = pack2bf(a0, a1); vh.y = pack2bf(a2, a3);
        vl.x = pack2bf(a0 - bfhi(a0), a1 - bfhi(a1));
        vl.y = pack2bf(a2 - bfhi(a2), a3 - bfhi(a3));
        const int off = (b*128 + (m*16 + 4*g)*2) ^ swzx;
        *(u32x2*)(scr + off)        = vh;
        *(u32x2*)(scr + 2048 + off) = vl;
    }
    __builtin_amdgcn_wave_barrier();
    // ---- L1: B-frags from ybuf ----
    bf16x8 Bh0, Bh1, Bl0, Bl1;
    {
        const int o0 = (b*128 + 16*g) ^ swzx;
        const int o1 = (b*128 + 64 + 16*g) ^ swzx;
        Bh0 = *(const bf16x8*)(scr + o0);
        Bh1 = *(const bf16x8*)(scr + o1);
        Bl0 = *(const bf16x8*)(scr + 2048 + o0);
        Bl1 = *(const bf16x8*)(scr + 2048 + o1);
    }
    __builtin_amdgcn_wave_barrier();
#pragma unroll
    for (int m = 0; m < 8; ++m) {
        f32x4 acc = {0.f, 0.f, 0.f, 0.f};
        const bf16x8 A0 = *(const bf16x8*)(wf + (m*2+0)*1024 + lane*16);
        const bf16x8 A1 = *(const bf16x8*)(wf + (m*2+1)*1024 + lane*16);
        acc = __builtin_amdgcn_mfma_f32_16x16x32_bf16(A0, Bh0, acc, 0, 0, 0);
        acc = __builtin_amdgcn_mfma_f32_16x16x32_bf16(A1, Bh1, acc, 0, 0, 0);
        acc = __builtin_amdgcn_mfma_f32_16x16x32_bf16(A0, Bl0, acc, 0, 0, 0);
        acc = __builtin_amdgcn_mfma_f32_16x16x32_bf16(A1, Bl1, acc, 0, 0, 0);
        const f4v bia = *(const f4v*)(biasf + m*16 + 4*g);
        const float v0 = fmaxf(acc[0] + bia.x, 0.f);
        const float v1 = fmaxf(acc[1] + bia.y, 0.f);
        const float v2 = fmaxf(acc[2] + bia.z, 0.f);
        const float v3 = fmaxf(acc[3] + bia.w, 0.f);
        u32x2 vh, vl;
        vh.x = pack2bf(v0, v1); vh.y = pack2bf(v2, v3);
        vl.x = pack2bf(v0 - bfhi(v0), v1 - bfhi(v1));
        vl.y = pack2bf(v2 - bfhi(v2), v3 - bfhi(v3));
        const int off = (b*256 + (m*16 + 4*g)*2) ^ swzx;
        *(u32x2*)(scr + 4096 + off) = vh;     // h1_hi
        *(u32x2*)(scr + off)        = vl;     // h1_lo (ybuf dead)
    }
    __builtin_amdgcn_wave_barrier();
    // ---- L2 ----
    bf16x8 B2h[4], B2l[4];
#pragma unroll
    for (int kt = 0; kt < 4; ++kt) {
        const int off = (b*256 + 64*kt + 16*g) ^ swzx;
        B2h[kt] = *(const bf16x8*)(scr + 4096 + off);
        B2l[kt] = *(const bf16x8*)(scr + off);
    }
    __builtin_amdgcn_wave_barrier();
#pragma unroll
    for (int m = 0; m < 8; ++m) {
        f32x4 acc = {0.f, 0.f, 0.f, 0.f};
#pragma unroll
        for (int kt = 0; kt < 4; ++kt) {
            const bf16x8 A = *(const bf16x8*)(wf + 16384 + (m*4+kt)*1024 + lane*16);
            acc = __builtin_amdgcn_mfma_f32_16x16x32_bf16(A, B2h[kt], acc, 0, 0, 0);
            acc = __builtin_amdgcn_mfma_f32_16x16x32_bf16(A, B2l[kt], acc, 0, 0, 0);
        }
        const f4v bia = *(const f4v*)(biasf + 128 + m*16 + 4*g);
        const float v0 = fmaxf(acc[0] + bia.x, 0.f);
        const float v1 = fmaxf(acc[1] + bia.y, 0.f);
        const float v2 = fmaxf(acc[2] + bia.z, 0.f);
        const float v3 = fmaxf(acc[3] + bia.w, 0.f);
        u32x2 vh;
        vh.x = pack2bf(v0, v1); vh.y = pack2bf(v2, v3);
        const int off = (b*256 + (m*16 + 4*g)*2) ^ swzx;
        *(u32x2*)(scr + off) = vh;            // h2_hi (h1_lo dead)
    }
    __builtin_amdgcn_wave_barrier();
    // ---- L3 ----
    bf16x8 B3[4];
#pragma unroll
    for (int kt = 0; kt < 4; ++kt)
        B3[kt] = *(const bf16x8*)(scr + ((b*256 + 64*kt + 16*g) ^ swzx));
    __builtin_amdgcn_wave_barrier();
#pragma unroll
    for (int m = 0; m < 4; ++m) {
        f32x4 acc = {0.f, 0.f, 0.f, 0.f};
#pragma unroll
        for (int kt = 0; kt < 4; ++kt) {
            const bf16x8 A = *(const bf16x8*)(wf + 49152 + (m*4+kt)*1024 + lane*16);
            acc = __builtin_amdgcn_mfma_f32_16x16x32_bf16(A, B3[kt], acc, 0, 0, 0);
        }
        const f4v bia = *(const f4v*)(biasf + 256 + m*16 + 4*g);
        kout[4*m+0] = acc[0] + bia.x;
        kout[4*m+1] = acc[1] + bia.y;
        kout[4*m+2] = acc[2] + bia.z;
        kout[4*m+3] = acc[3] + bia.w;
    }
}

__global__ __launch_bounds__(NTHREADS)
__attribute__((amdgpu_waves_per_eu(2, 2)))
void ode_kernel(
    const float* __restrict__ x,
    const float* __restrict__ gW1, const float* __restrict__ gb1,
    const float* __restrict__ gW2, const float* __restrict__ gb2,
    const float* __restrict__ gW3, const float* __restrict__ gb3,
    float* __restrict__ Y, float* __restrict__ ws)
{
    extern __shared__ float lds[];
    char*  ldsb  = (char*)lds;
    short* wfrag = (short*)ldsb;
    float* biasf = (float*)(ldsb + 131072);

    const int tid  = threadIdx.x;
    const int lane = tid & 63;
    const int wid  = tid >> 6;
    const int bid  = blockIdx.x;
    const int b    = lane & 15;
    const int g    = lane >> 4;
    const int swzx = (b & 7) << 4;

    // ---- stage weights as frag-linear bf16 tiles (once) ----
    for (int i = tid; i < 8192; i += NTHREADS) {       // W1: 16 tiles (m*2+kt)
        const int t = i >> 9, l = (i >> 3) & 63, j = i & 7;
        const int m = t >> 1, kt = t & 1;
        const int row = kt*32 + (l>>4)*8 + j, col = m*16 + (l&15);
        wfrag[i] = (short)bfr(gW1[row*128 + col]);
    }
    for (int i = tid; i < 16384; i += NTHREADS) {      // W2: 32 tiles (m*4+kt)
        const int t = i >> 9, l = (i >> 3) & 63, j = i & 7;
        const int m = t >> 2, kt = t & 3;
        const int row = kt*32 + (l>>4)*8 + j, col = m*16 + (l&15);
        wfrag[8192 + i] = (short)bfr(gW2[row*128 + col]);
    }
    for (int i = tid; i < 8192; i += NTHREADS) {       // W3: 16 tiles (m*4+kt)
        const int t = i >> 9, l = (i >> 3) & 63, j = i & 7;
        const int m = t >> 2, kt = t & 3;
        const int row = kt*32 + (l>>4)*8 + j, col = m*16 + (l&15);
        wfrag[24576 + i] = (short)bfr(gW3[row*64 + col]);
    }
    for (int i = tid; i < 128; i += NTHREADS) biasf[i]       = gb1[i];
    for (int i = tid; i < 128; i += NTHREADS) biasf[128 + i] = gb2[i];
    for (int i = tid; i < 64;  i += NTHREADS) biasf[256 + i] = gb3[i];
    __syncthreads();

    char* scr = ldsb + 65536 + wid * 8192;
    float* wavepart = ws;                     // [2][2048] ping-pong

    cg::grid_group grid = cg::this_grid();
    const int row0 = bid * 128 + wid * 16;

    // persistent state: lane owns batch row0+b, dims m*16+4g+r  (idx = m*4+r)
    float y[16], k1[16];

    // ---- prepass: y = x; k1 = f(y) ----
    {
        float ysv[16];
#pragma unroll
        for (int m = 0; m < 4; ++m) {
            const f4v v = *(const f4v*)(x + (row0 + b) * 64 + m*16 + 4*g);
            ysv[4*m+0] = v.x; ysv[4*m+1] = v.y; ysv[4*m+2] = v.z; ysv[4*m+3] = v.w;
        }
#pragma unroll
        for (int i = 0; i < 16; ++i) y[i] = ysv[i];
        feval16(ldsb, biasf, scr, lane, b, g, swzx, ysv, k1);
    }

    float t = 0.0f, h = H0_C;
    bool done = false;

#pragma unroll 1
    for (int iter = 0; iter < 64; ++iter) {
        const float hs = fminf(h, 1.0f - t);
        float sq = 0.0f;
        float y5[16], k7[16];

        // ---- straight-line dopri5 stages (precise liveness; k2 dies at s4,
        //      k3..k6 die at the y5/errp computation, before the k7 feval) ----
        {
            float ysv[16];
            float k2[16], k3[16], k4[16], k5[16], k6[16], errp[16];

#pragma unroll
            for (int i = 0; i < 16; ++i) ysv[i] = y[i] + hs * (A21 * k1[i]);
            feval16(ldsb, biasf, scr, lane, b, g, swzx, ysv, k2);

#pragma unroll
            for (int i = 0; i < 16; ++i) ysv[i] = y[i] + hs * (A31 * k1[i] + A32 * k2[i]);
            feval16(ldsb, biasf, scr, lane, b, g, swzx, ysv, k3);

#pragma unroll
            for (int i = 0; i < 16; ++i) ysv[i] = y[i] + hs * (A41 * k1[i] + A42 * k2[i] + A43 * k3[i]);
            feval16(ldsb, biasf, scr, lane, b, g, swzx, ysv, k4);

#pragma unroll
            for (int i = 0; i < 16; ++i) ysv[i] = y[i] + hs * (A51 * k1[i] + A52 * k2[i] + A53 * k3[i] + A54 * k4[i]);
            feval16(ldsb, biasf, scr, lane, b, g, swzx, ysv, k5);

#pragma unroll
            for (int i = 0; i < 16; ++i) ysv[i] = y[i] + hs * (A61 * k1[i] + A62 * k2[i] + A63 * k3[i] + A64 * k4[i] + A65 * k5[i]);
            feval16(ldsb, biasf, scr, lane, b, g, swzx, ysv, k6);   // k2 dead

#pragma unroll
            for (int i = 0; i < 16; ++i) {
                ysv[i]  = y[i] + hs * (BB1 * k1[i] + BB3 * k3[i] + BB4 * k4[i] + BB5 * k5[i] + BB6 * k6[i]);
                y5[i]   = ysv[i];
                errp[i] = hs * (E1 * k1[i] + E3 * k3[i] + E4 * k4[i] + E5 * k5[i] + E6 * k6[i]);
            }                                                        // k3..k6 dead
            feval16(ldsb, biasf, scr, lane, b, g, swzx, ysv, k7);

#pragma unroll
            for (int i = 0; i < 16; ++i) {
                const float er = errp[i] + hs * (E7 * k7[i]);
                const float sc = ATOL_C + RTOL_C * fmaxf(fabsf(y[i]), fabsf(y5[i]));
                const float q = er / sc;
                sq += q * q;
            }
        }

        // wave butterfly reduce (bitwise identical on all lanes)
#pragma unroll
        for (int off = 32; off > 0; off >>= 1) sq += __shfl_xor(sq, off);
        if (lane == 0)
            __hip_atomic_store(&wavepart[(iter & 1) * 2048 + bid * 8 + wid], sq,
                               __ATOMIC_RELEASE, __HIP_MEMORY_SCOPE_AGENT);
        grid.sync();

        // every wave redundantly sums all 2048 partials in identical fixed order
        float psum = 0.0f;
        const float* wp = wavepart + (iter & 1) * 2048;
#pragma unroll 4
        for (int k = 0; k < 32; ++k)
            psum += __hip_atomic_load(&wp[lane + 64 * k], __ATOMIC_RELAXED, __HIP_MEMORY_SCOPE_AGENT);
#pragma unroll
        for (int off = 32; off > 0; off >>= 1) psum += __shfl_xor(psum, off);
        const float tot = psum;

        const float err_norm = sqrtf(tot * (1.0f / (float)(BATCH * 64)));
        const bool accept = (err_norm <= 1.0f) && (!done);
        float factor = SAFETY_C * powf(fmaxf(err_norm, 1e-10f), -0.2f);
        factor = fminf(fmaxf(factor, MINFAC_C), MAXFAC_C);

        if (accept) {
#pragma unroll
            for (int i = 0; i < 16; ++i) { y[i] = y5[i]; k1[i] = k7[i]; }
            t = t + hs;
        }
        h = hs * factor;
        done = done || (t >= T_DONE);
        if (done) break;   // uniform: identical err_norm in every block
    }

    // final store
#pragma unroll
    for (int m = 0; m < 4; ++m) {
        f4v v;
        v.x = y[4*m+0]; v.y = y[4*m+1]; v.z = y[4*m+2]; v.w = y[4*m+3];
        *(f4v*)(Y + (row0 + b) * 64 + m*16 + 4*g) = v;
    }
}

extern "C" void kernel_launch(void* const* d_in, const int* in_sizes, int n_in,
                              void* d_out, int out_size, void* d_ws, size_t ws_size,
                              hipStream_t stream) {
    const float* x  = (const float*)d_in[0];
    const float* W1 = (const float*)d_in[1];
    const float* b1 = (const float*)d_in[2];
    const float* W2 = (const float*)d_in[3];
    const float* b2 = (const float*)d_in[4];
    const float* W3 = (const float*)d_in[5];
    const float* b3 = (const float*)d_in[6];
    float* Y  = (float*)d_out;
    float* ws = (float*)d_ws;

    const size_t need = (size_t)(2 * 2048) * sizeof(float);
    if (ws_size < need) return;

    (void)hipFuncSetAttribute(reinterpret_cast<const void*>(ode_kernel),
                              hipFuncAttributeMaxDynamicSharedMemorySize, LDS_BYTES);

    void* args[] = {(void*)&x, (void*)&W1, (void*)&b1, (void*)&W2, (void*)&b2,
                    (void*)&W3, (void*)&b3, (void*)&Y, (void*)&ws};
    (void)hipLaunchCooperativeKernel(reinterpret_cast<const void*>(ode_kernel),
                                     dim3(NBLOCKS), dim3(NTHREADS),
                                     args, LDS_BYTES, stream);
}